// Round 1
// baseline (473.812 us; speedup 1.0000x reference)
//
#include <hip/hip_runtime.h>
#include <hip/hip_bf16.h>
#include <math.h>

// Problem constants (MultiQueryAttention: B=2, S=2048, D=1024, H=16, hd=64)
#define BB 2
#define SS 2048
#define DD 1024
#define NH 16
#define HD 64
#define MM (BB * SS)  // 4096 tokens

typedef __hip_bfloat16 bf16;
typedef __bf16 bf16_t;
typedef __attribute__((ext_vector_type(8))) __bf16 bf16x8;
typedef __attribute__((ext_vector_type(4))) __bf16 bf16x4;
typedef __attribute__((ext_vector_type(4))) float floatx4;

// ---------------- runtime dtype detection (parallel) ----------------
// flag==1 -> external tensors are fp32 (the proven world); flag==0 -> bf16.
__global__ void detect_dtype(const unsigned int* __restrict__ x, int* __restrict__ flag) {
    const int tid = threadIdx.x;  // 64 lanes
    int good = 0;
    for (int i = tid; i < 256; i += 64) {
        unsigned int bits = (x[i] & 0xFFFFu) << 16;
        float v = __uint_as_float(bits);
        float av = fabsf(v);
        if (av == 0.f || (av >= 9.5367431640625e-7f && av <= 64.f)) good++;
    }
#pragma unroll
    for (int s = 1; s < 64; s <<= 1) good += __shfl_xor(good, s);
    if (tid == 0) *flag = (good >= 240) ? 0 : 1;
}

// ---------------- MFMA projection GEMMs ----------------
// 128(rows)x64(cols) tiles, BK=32, 4 waves (each: 32 rows x 64 cols, 8 MFMA
// per iter).
#define BK 32
#define KP 40   // LDS row stride in bf16 elems

__device__ __forceinline__ bf16x4 cvt4(float4 v) {
    bf16x4 o;
    o[0] = (bf16_t)v.x; o[1] = (bf16_t)v.y; o[2] = (bf16_t)v.z; o[3] = (bf16_t)v.w;
    return o;
}

// Fused QKV projection. cb 0..15 -> QA cols cb*64..; cb 16 -> Kp; cb 17 -> VpT.
__global__ __launch_bounds__(256) void proj_qkv(const void* __restrict__ X,
                                                const void* __restrict__ Wq,
                                                const void* __restrict__ Wk,
                                                const void* __restrict__ Wv,
                                                bf16_t* __restrict__ QA,
                                                bf16_t* __restrict__ Kp,
                                                bf16_t* __restrict__ VpT,
                                                const int* __restrict__ flag) {
    const int f = *flag;  // 1 => fp32 inputs

    __shared__ bf16_t As[128 * KP];
    __shared__ bf16_t Ws[64 * KP];

    const int tid = threadIdx.x;
    const int wave = tid >> 6, lane = tid & 63;
    const int lo = lane & 15, quad = lane >> 4;
    const int rb = wave * 32;               // wave's row band
    const int cb = blockIdx.x;              // 0..17
    const int rowBase = blockIdx.y * 128;

    floatx4 acc[2][4];
#pragma unroll
    for (int i = 0; i < 2; i++)
#pragma unroll
        for (int j = 0; j < 4; j++) acc[i][j] = (floatx4){0.f, 0.f, 0.f, 0.f};

    if (f) {
        const int rA = tid >> 3, sg = tid & 7;
        const float* arow[4];
        const float* wrow[2];
#pragma unroll
        for (int p = 0; p < 4; p++)
            arow[p] = (const float*)X + (size_t)(rowBase + rA + 32 * p) * DD;
#pragma unroll
        for (int p = 0; p < 2; p++) {
            int row = rA + 32 * p;  // 0..63
            if (cb < 16)       wrow[p] = (const float*)Wq + (size_t)(cb * 64 + row) * DD;
            else if (cb == 16) wrow[p] = (const float*)Wk + (size_t)row * DD;
            else               wrow[p] = (const float*)Wv + (size_t)row * DD;
        }
        float4 aR[4], wR[2];
#pragma unroll
        for (int p = 0; p < 4; p++) aR[p] = *(const float4*)(arow[p] + sg * 4);
#pragma unroll
        for (int p = 0; p < 2; p++) wR[p] = *(const float4*)(wrow[p] + sg * 4);

        for (int k0 = 0; k0 < DD; k0 += BK) {
            __syncthreads();
#pragma unroll
            for (int p = 0; p < 4; p++)
                *(bf16x4*)&As[(rA + 32 * p) * KP + sg * 4] = cvt4(aR[p]);
#pragma unroll
            for (int p = 0; p < 2; p++)
                *(bf16x4*)&Ws[(rA + 32 * p) * KP + sg * 4] = cvt4(wR[p]);
            __syncthreads();
            if (k0 + BK < DD) {
#pragma unroll
                for (int p = 0; p < 4; p++) aR[p] = *(const float4*)(arow[p] + k0 + BK + sg * 4);
#pragma unroll
                for (int p = 0; p < 2; p++) wR[p] = *(const float4*)(wrow[p] + k0 + BK + sg * 4);
            }
            bf16x8 afr[2], bfr[4];
#pragma unroll
            for (int i = 0; i < 2; i++)
                afr[i] = *(const bf16x8*)&As[(rb + i * 16 + lo) * KP + quad * 8];
#pragma unroll
            for (int j = 0; j < 4; j++)
                bfr[j] = *(const bf16x8*)&Ws[(j * 16 + lo) * KP + quad * 8];
#pragma unroll
            for (int i = 0; i < 2; i++)
#pragma unroll
                for (int j = 0; j < 4; j++)
                    acc[i][j] = __builtin_amdgcn_mfma_f32_16x16x32_bf16(afr[i], bfr[j], acc[i][j], 0, 0, 0);
        }
    } else {
        const int rA = tid >> 2, sg = tid & 3;   // rA 0..63
        const bf16_t* arow[2];
        const bf16_t* wrow;
#pragma unroll
        for (int p = 0; p < 2; p++)
            arow[p] = (const bf16_t*)X + (size_t)(rowBase + rA + 64 * p) * DD;
        if (cb < 16)       wrow = (const bf16_t*)Wq + (size_t)(cb * 64 + rA) * DD;
        else if (cb == 16) wrow = (const bf16_t*)Wk + (size_t)rA * DD;
        else               wrow = (const bf16_t*)Wv + (size_t)rA * DD;
        bf16x8 aR[2], wR;
#pragma unroll
        for (int p = 0; p < 2; p++) aR[p] = *(const bf16x8*)(arow[p] + sg * 8);
        wR = *(const bf16x8*)(wrow + sg * 8);

        for (int k0 = 0; k0 < DD; k0 += BK) {
            __syncthreads();
#pragma unroll
            for (int p = 0; p < 2; p++)
                *(bf16x8*)&As[(rA + 64 * p) * KP + sg * 8] = aR[p];
            *(bf16x8*)&Ws[rA * KP + sg * 8] = wR;
            __syncthreads();
            if (k0 + BK < DD) {
#pragma unroll
                for (int p = 0; p < 2; p++) aR[p] = *(const bf16x8*)(arow[p] + k0 + BK + sg * 8);
                wR = *(const bf16x8*)(wrow + k0 + BK + sg * 8);
            }
            bf16x8 afr[2], bfr[4];
#pragma unroll
            for (int i = 0; i < 2; i++)
                afr[i] = *(const bf16x8*)&As[(rb + i * 16 + lo) * KP + quad * 8];
#pragma unroll
            for (int j = 0; j < 4; j++)
                bfr[j] = *(const bf16x8*)&Ws[(j * 16 + lo) * KP + quad * 8];
#pragma unroll
            for (int i = 0; i < 2; i++)
#pragma unroll
                for (int j = 0; j < 4; j++)
                    acc[i][j] = __builtin_amdgcn_mfma_f32_16x16x32_bf16(afr[i], bfr[j], acc[i][j], 0, 0, 0);
        }
    }

#pragma unroll
    for (int i = 0; i < 2; i++)
#pragma unroll
        for (int j = 0; j < 4; j++)
#pragma unroll
            for (int reg = 0; reg < 4; reg++) {
                int row = rowBase + rb + i * 16 + quad * 4 + reg;  // token
                int col = j * 16 + lo;                              // 0..63
                bf16_t val = (bf16_t)acc[i][j][reg];
                if (cb < 16)       QA[(size_t)row * DD + cb * 64 + col] = val;
                else if (cb == 16) Kp[(size_t)row * HD + col] = val;
                else               VpT[((size_t)(row >> 11) * HD + col) * SS + (row & (SS - 1))] = val;
            }
}

__global__ __launch_bounds__(256) void proj_o(const bf16_t* __restrict__ AO,
                                              const void* __restrict__ Wo,
                                              void* __restrict__ Cout,
                                              const int* __restrict__ flag) {
    const int f = *flag;

    __shared__ bf16_t As[128 * KP];
    __shared__ bf16_t Ws[64 * KP];

    const int tid = threadIdx.x;
    const int wave = tid >> 6, lane = tid & 63;
    const int lo = lane & 15, quad = lane >> 4;
    const int rb = wave * 32;
    const int colBase = blockIdx.x * 64;
    const int rowBase = blockIdx.y * 128;

    floatx4 acc[2][4];
#pragma unroll
    for (int i = 0; i < 2; i++)
#pragma unroll
        for (int j = 0; j < 4; j++) acc[i][j] = (floatx4){0.f, 0.f, 0.f, 0.f};

    // A staging (bf16 always)
    const int rA2 = tid >> 2, sgA = tid & 3;
    const bf16_t* arow[2] = {AO + (size_t)(rowBase + rA2) * DD,
                             AO + (size_t)(rowBase + rA2 + 64) * DD};
    bf16x8 aR[2];
#pragma unroll
    for (int p = 0; p < 2; p++) aR[p] = *(const bf16x8*)(arow[p] + sgA * 8);

    if (f) {
        const int rW = tid >> 3, sgW = tid & 7;
        const float* wrow[2];
#pragma unroll
        for (int p = 0; p < 2; p++)
            wrow[p] = (const float*)Wo + (size_t)(colBase + rW + 32 * p) * DD;
        float4 wR[2];
#pragma unroll
        for (int p = 0; p < 2; p++) wR[p] = *(const float4*)(wrow[p] + sgW * 4);

        for (int k0 = 0; k0 < DD; k0 += BK) {
            __syncthreads();
#pragma unroll
            for (int p = 0; p < 2; p++)
                *(bf16x8*)&As[(rA2 + 64 * p) * KP + sgA * 8] = aR[p];
#pragma unroll
            for (int p = 0; p < 2; p++)
                *(bf16x4*)&Ws[(rW + 32 * p) * KP + sgW * 4] = cvt4(wR[p]);
            __syncthreads();
            if (k0 + BK < DD) {
#pragma unroll
                for (int p = 0; p < 2; p++) aR[p] = *(const bf16x8*)(arow[p] + k0 + BK + sgA * 8);
#pragma unroll
                for (int p = 0; p < 2; p++) wR[p] = *(const float4*)(wrow[p] + k0 + BK + sgW * 4);
            }
            bf16x8 afr[2], bfr[4];
#pragma unroll
            for (int i = 0; i < 2; i++)
                afr[i] = *(const bf16x8*)&As[(rb + i * 16 + lo) * KP + quad * 8];
#pragma unroll
            for (int j = 0; j < 4; j++)
                bfr[j] = *(const bf16x8*)&Ws[(j * 16 + lo) * KP + quad * 8];
#pragma unroll
            for (int i = 0; i < 2; i++)
#pragma unroll
                for (int j = 0; j < 4; j++)
                    acc[i][j] = __builtin_amdgcn_mfma_f32_16x16x32_bf16(afr[i], bfr[j], acc[i][j], 0, 0, 0);
        }
    } else {
        const bf16_t* wrow = (const bf16_t*)Wo + (size_t)(colBase + rA2) * DD;
        bf16x8 wR = *(const bf16x8*)(wrow + sgA * 8);

        for (int k0 = 0; k0 < DD; k0 += BK) {
            __syncthreads();
#pragma unroll
            for (int p = 0; p < 2; p++)
                *(bf16x8*)&As[(rA2 + 64 * p) * KP + sgA * 8] = aR[p];
            *(bf16x8*)&Ws[rA2 * KP + sgA * 8] = wR;
            __syncthreads();
            if (k0 + BK < DD) {
#pragma unroll
                for (int p = 0; p < 2; p++) aR[p] = *(const bf16x8*)(arow[p] + k0 + BK + sgA * 8);
                wR = *(const bf16x8*)(wrow + k0 + BK + sgA * 8);
            }
            bf16x8 afr[2], bfr[4];
#pragma unroll
            for (int i = 0; i < 2; i++)
                afr[i] = *(const bf16x8*)&As[(rb + i * 16 + lo) * KP + quad * 8];
#pragma unroll
            for (int j = 0; j < 4; j++)
                bfr[j] = *(const bf16x8*)&Ws[(j * 16 + lo) * KP + quad * 8];
#pragma unroll
            for (int i = 0; i < 2; i++)
#pragma unroll
                for (int j = 0; j < 4; j++)
                    acc[i][j] = __builtin_amdgcn_mfma_f32_16x16x32_bf16(afr[i], bfr[j], acc[i][j], 0, 0, 0);
        }
    }

#pragma unroll
    for (int i = 0; i < 2; i++)
#pragma unroll
        for (int j = 0; j < 4; j++)
#pragma unroll
            for (int reg = 0; reg < 4; reg++) {
                int row = rowBase + rb + i * 16 + quad * 4 + reg;
                int col = colBase + j * 16 + lo;
                size_t idx = (size_t)row * DD + col;
                if (f) ((float*)Cout)[idx] = acc[i][j][reg];
                else   ((bf16_t*)Cout)[idx] = (bf16_t)acc[i][j][reg];
            }
}

// ---------------- barrier-free MFMA flash attention, balanced key-split ----
// 512-thread blocks (8 waves), pair (x, 63-x): exactly 65 key-tiles of work
// per block regardless of x -> block balance by construction. Waves are
// assigned proportionally: na waves serve qt=x (minimizing the max wave's
// tile count, worst case 10 vs the old 32), the rest serve qt=63-x. Each
// wave computes an online-softmax partial over its contiguous key range;
// partials merge with a binary tree within each wave group through LDS
// (buffers union the dead P-staging region). __launch_bounds__(512,8)
// keeps VGPR<=64 -> 4 blocks/CU = 32 waves/CU (100% occupancy).
#define PSTR 40
#define ALOG2E 0.18033688011112042f   // (1/sqrt(64)) * log2(e)

__global__ __launch_bounds__(512, 8) void attn_mfma(const bf16_t* Q,
                                                    const bf16_t* __restrict__ K,
                                                    const bf16_t* __restrict__ Vt,
                                                    bf16_t* O) {
    const int h = blockIdx.y, b = blockIdx.z;
    const int tid = threadIdx.x;
    const int wq = tid >> 6, lane = tid & 63;
    const int lo = lane & 15, quad = lane >> 4;
    const int x = blockIdx.x;           // 0..31 -> pair (x, 63-x)

    // --- proportional wave->q-tile assignment (minimize max wave tiles) ---
    const int nA = x + 1;               // key-tiles for qt = x (pair total 65)
    int na = 1, bestc = 0x7fffffff;
#pragma unroll
    for (int a = 1; a <= 7; ++a) {
        int cA = (nA + a - 1) / a;
        int cB = (65 - nA + (7 - a)) / (8 - a);
        int c = cA > cB ? cA : cB;
        if (c < bestc) { bestc = c; na = a; }
    }
    int qt, pos, gs;
    if (wq < na) { qt = x;      pos = wq;      gs = na; }
    else         { qt = 63 - x; pos = wq - na; gs = 8 - na; }
    const int q0 = qt * 32;
    const int n = qt + 1;               // total key-tiles for this q-tile
    const int itS = (n * pos) / gs;
    const int itE = (n * (pos + 1)) / gs;

    // --- LDS: P staging (per-wave, loop phase) unions merge buffers ---
    __shared__ __align__(16) char smem[4 * 32 * 64 * 4];  // 32768 B
    __shared__ float MrgML[4][2][2][16];                  // [buf][s][m/l][lo]
    bf16_t* Pw = (bf16_t*)smem + wq * (32 * PSTR);        // 8 x 2560 B = 20480 B
    float (*MrgO)[32 * 64] = (float (*)[32 * 64])smem;    // 4 bufs x 8 KB

    // Q frags (B operand: n=q, k=dim)
    bf16x8 qf[2][2];
#pragma unroll
    for (int s = 0; s < 2; s++)
#pragma unroll
        for (int hf = 0; hf < 2; hf++)
            qf[s][hf] = *(const bf16x8*)(Q + ((size_t)(b * SS + q0 + s * 16 + lo)) * DD +
                                         h * HD + hf * 32 + quad * 8);

    floatx4 Oacc[2][4];
    float m_i[2], l_i[2];
#pragma unroll
    for (int s = 0; s < 2; s++) {
#pragma unroll
        for (int dt = 0; dt < 4; dt++) Oacc[s][dt] = (floatx4){0.f, 0.f, 0.f, 0.f};
        m_i[s] = -1e30f; l_i[s] = 0.f;
    }

    const bf16_t* Kb = K + (size_t)b * SS * HD;
    const bf16_t* Vb = Vt + (size_t)b * HD * SS;

    if (itS < itE) {
        // preload K tile itS
        bf16x8 kf[2][2];
#pragma unroll
        for (int kt = 0; kt < 2; kt++)
#pragma unroll
            for (int hf = 0; hf < 2; hf++)
                kf[kt][hf] = *(const bf16x8*)(Kb + (size_t)(itS * 32 + kt * 16 + lo) * HD +
                                              hf * 32 + quad * 8);

        for (int it = itS; it < itE; it++) {
            const int t0 = it * 32;

            bf16x8 vf[4];
#pragma unroll
            for (int dt = 0; dt < 4; dt++)
                vf[dt] = *(const bf16x8*)(Vb + (size_t)(dt * 16 + lo) * SS + t0 + quad * 8);

            bf16x8 kn[2][2];
            if (it + 1 < itE) {
#pragma unroll
                for (int kt = 0; kt < 2; kt++)
#pragma unroll
                    for (int hf = 0; hf < 2; hf++)
                        kn[kt][hf] = *(const bf16x8*)(Kb + (size_t)(t0 + 32 + kt * 16 + lo) * HD +
                                                      hf * 32 + quad * 8);
            }

            // S^T = K.Q^T
            floatx4 st[2][2];
#pragma unroll
            for (int s = 0; s < 2; s++)
#pragma unroll
                for (int kt = 0; kt < 2; kt++) {
                    floatx4 z = (floatx4){0.f, 0.f, 0.f, 0.f};
                    z = __builtin_amdgcn_mfma_f32_16x16x32_bf16(kf[kt][0], qf[s][0], z, 0, 0, 0);
                    z = __builtin_amdgcn_mfma_f32_16x16x32_bf16(kf[kt][1], qf[s][1], z, 0, 0, 0);
                    st[s][kt] = z;
                }

            if (it == qt) {  // diagonal tile (always last pos of the group)
#pragma unroll
                for (int s = 0; s < 2; s++) {
                    int q = q0 + s * 16 + lo;
#pragma unroll
                    for (int kt = 0; kt < 2; kt++)
#pragma unroll
                        for (int reg = 0; reg < 4; reg++)
                            if (t0 + kt * 16 + quad * 4 + reg > q) st[s][kt][reg] = -1e30f;
                }
            }

            // online softmax, lane-owned q-rows
#pragma unroll
            for (int s = 0; s < 2; s++) {
                float mx = fmaxf(fmaxf(fmaxf(st[s][0][0], st[s][0][1]), fmaxf(st[s][0][2], st[s][0][3])),
                                 fmaxf(fmaxf(st[s][1][0], st[s][1][1]), fmaxf(st[s][1][2], st[s][1][3])));
                mx = fmaxf(mx, __shfl_xor(mx, 16));
                mx = fmaxf(mx, __shfl_xor(mx, 32));
                float mn = fmaxf(m_i[s], mx);
                float al = exp2f((m_i[s] - mn) * ALOG2E);
                m_i[s] = mn;
                float mnA = mn * ALOG2E;
                float p[2][4];
#pragma unroll
                for (int kt = 0; kt < 2; kt++)
#pragma unroll
                    for (int reg = 0; reg < 4; reg++)
                        p[kt][reg] = exp2f(st[s][kt][reg] * ALOG2E - mnA);
                float rs = ((p[0][0] + p[0][1]) + (p[0][2] + p[0][3])) +
                           ((p[1][0] + p[1][1]) + (p[1][2] + p[1][3]));
                rs += __shfl_xor(rs, 16);
                rs += __shfl_xor(rs, 32);
                l_i[s] = l_i[s] * al + rs;
#pragma unroll
                for (int kt = 0; kt < 2; kt++) {
                    bf16x4 pk;
#pragma unroll
                    for (int reg = 0; reg < 4; reg++) pk[reg] = (bf16_t)p[kt][reg];
                    *(bf16x4*)&Pw[(s * 16 + lo) * PSTR + kt * 16 + quad * 4] = pk;
                }
#pragma unroll
                for (int dt = 0; dt < 4; dt++) Oacc[s][dt] *= al;
            }

            asm volatile("s_waitcnt lgkmcnt(0)" ::: "memory");

            // O^T += V^T . P^T
            bf16x8 pb[2];
#pragma unroll
            for (int s = 0; s < 2; s++)
                pb[s] = *(const bf16x8*)&Pw[(s * 16 + lo) * PSTR + quad * 8];
#pragma unroll
            for (int s = 0; s < 2; s++)
#pragma unroll
                for (int dt = 0; dt < 4; dt++)
                    Oacc[s][dt] = __builtin_amdgcn_mfma_f32_16x16x32_bf16(vf[dt], pb[s], Oacc[s][dt], 0, 0, 0);

#pragma unroll
            for (int kt = 0; kt < 2; kt++)
#pragma unroll
                for (int hf = 0; hf < 2; hf++) kf[kt][hf] = kn[kt][hf];
        }
    }

    // ---- binary-tree merge within each wave group (flash merge algebra) ----
    // Publishers (pos % 2*step == step) write (m,l,O^T) to buffer wq>>1;
    // combiners (pos % 2*step == 0, partner in range) fold partner's buffer
    // ((wq+step)>>1) into registers. Division deferred to the final store.
    for (int step = 1; step < 8; step <<= 1) {
        const bool pub = (pos & (2 * step - 1)) == step;
        const bool cmb = ((pos & (2 * step - 1)) == 0) && (pos + step < gs);
        __syncthreads();   // previous round's reads (and P-staging use) done
        if (pub) {
            float* Ob = MrgO[wq >> 1];
#pragma unroll
            for (int s = 0; s < 2; s++) {
#pragma unroll
                for (int dt = 0; dt < 4; dt++)
#pragma unroll
                    for (int reg = 0; reg < 4; reg++)
                        Ob[(s * 16 + dt * 4 + reg) * 64 + lane] = Oacc[s][dt][reg];
                if (quad == 0) {
                    MrgML[wq >> 1][s][0][lo] = m_i[s];
                    MrgML[wq >> 1][s][1][lo] = l_i[s];
                }
            }
        }
        __syncthreads();
        if (cmb) {
            const int bu = (wq + step) >> 1;
            const float* Ob = MrgO[bu];
#pragma unroll
            for (int s = 0; s < 2; s++) {
                float m1 = MrgML[bu][s][0][lo];
                float l1 = MrgML[bu][s][1][lo];
                float mm = fmaxf(m_i[s], m1);
                float a0 = exp2f((m_i[s] - mm) * ALOG2E);
                float a1 = exp2f((m1 - mm) * ALOG2E);
                m_i[s] = mm;
                l_i[s] = l_i[s] * a0 + l1 * a1;
#pragma unroll
                for (int dt = 0; dt < 4; dt++)
#pragma unroll
                    for (int reg = 0; reg < 4; reg++)
                        Oacc[s][dt][reg] = Oacc[s][dt][reg] * a0 +
                                           Ob[(s * 16 + dt * 4 + reg) * 64 + lane] * a1;
            }
        }
    }

    // ---- group leaders (pos==0: waves 0 and na) finalize + store ----
    if (pos == 0) {
#pragma unroll
        for (int s = 0; s < 2; s++) {
            float linv = 1.f / l_i[s];
            bf16_t* Orow = O + ((size_t)(b * SS + q0 + s * 16 + lo)) * DD + h * HD;
#pragma unroll
            for (int dt = 0; dt < 4; dt++) {
                bf16x4 ov;
#pragma unroll
                for (int reg = 0; reg < 4; reg++)
                    ov[reg] = (bf16_t)(Oacc[s][dt][reg] * linv);
                *(bf16x4*)&Orow[dt * 16 + quad * 4] = ov;
            }
        }
    }
}

// ---------------- launch ----------------
extern "C" void kernel_launch(void* const* d_in, const int* in_sizes, int n_in,
                              void* d_out, int out_size, void* d_ws, size_t ws_size,
                              hipStream_t stream) {
    const void* x  = d_in[0];
    const void* Wq = d_in[1];
    const void* Wk = d_in[2];
    const void* Wv = d_in[3];
    const void* Wo = d_in[4];
    // d_in[5] = causal mask — known tril, handled analytically in attn_mfma.

    // Workspace (~9.0 MB): [flag 256B] | QA bf16[4096,1024] (Q -> attention
    // output in-place) | Kp bf16[4096,64] | VpT bf16[2][64][2048]
    char* ws = (char*)d_ws;
    int* flag = (int*)ws;
    bf16_t* QA  = (bf16_t*)(ws + 256);
    bf16_t* Kp  = QA + (size_t)MM * DD;
    bf16_t* VpT = Kp + (size_t)MM * HD;

    detect_dtype<<<1, 64, 0, stream>>>((const unsigned int*)x, flag);

    // 128x64 tiles: 18x32 = 576 blocks (~2.25/CU)
    proj_qkv<<<dim3(18, MM / 128), dim3(256), 0, stream>>>(x, Wq, Wk, Wv, QA, Kp, VpT, flag);

    // Balanced pair-blocks: 32 x NH x BB = 1024 blocks of 512 thr (4/CU, 32 waves/CU)
    attn_mfma<<<dim3(32, NH, BB), dim3(512), 0, stream>>>(QA, Kp, VpT, QA);

    // 128x64 tiles: 16x32 = 512 blocks (2/CU)
    proj_o<<<dim3(16, MM / 128), dim3(256), 0, stream>>>(QA, Wo, d_out, flag);
}

// Round 2
// 220.766 us; speedup vs baseline: 2.1462x; 2.1462x over previous
//
#include <hip/hip_runtime.h>
#include <hip/hip_bf16.h>
#include <math.h>

// Problem constants (MultiQueryAttention: B=2, S=2048, D=1024, H=16, hd=64)
#define BB 2
#define SS 2048
#define DD 1024
#define NH 16
#define HD 64
#define MM (BB * SS)  // 4096 tokens

typedef __hip_bfloat16 bf16;
typedef __bf16 bf16_t;
typedef __attribute__((ext_vector_type(8))) __bf16 bf16x8;
typedef __attribute__((ext_vector_type(4))) __bf16 bf16x4;
typedef __attribute__((ext_vector_type(4))) float floatx4;

// ---------------- runtime dtype detection (parallel) ----------------
// flag==1 -> external tensors are fp32 (the proven world); flag==0 -> bf16.
__global__ void detect_dtype(const unsigned int* __restrict__ x, int* __restrict__ flag) {
    const int tid = threadIdx.x;  // 64 lanes
    int good = 0;
    for (int i = tid; i < 256; i += 64) {
        unsigned int bits = (x[i] & 0xFFFFu) << 16;
        float v = __uint_as_float(bits);
        float av = fabsf(v);
        if (av == 0.f || (av >= 9.5367431640625e-7f && av <= 64.f)) good++;
    }
#pragma unroll
    for (int s = 1; s < 64; s <<= 1) good += __shfl_xor(good, s);
    if (tid == 0) *flag = (good >= 240) ? 0 : 1;
}

// ---------------- MFMA projection GEMMs ----------------
// 128(rows)x64(cols) tiles, BK=32, 4 waves (each: 32 rows x 64 cols, 8 MFMA
// per iter).
#define BK 32
#define KP 40   // LDS row stride in bf16 elems

__device__ __forceinline__ bf16x4 cvt4(float4 v) {
    bf16x4 o;
    o[0] = (bf16_t)v.x; o[1] = (bf16_t)v.y; o[2] = (bf16_t)v.z; o[3] = (bf16_t)v.w;
    return o;
}

// Fused QKV projection. cb 0..15 -> QA cols cb*64..; cb 16 -> Kp; cb 17 -> VpT.
__global__ __launch_bounds__(256) void proj_qkv(const void* __restrict__ X,
                                                const void* __restrict__ Wq,
                                                const void* __restrict__ Wk,
                                                const void* __restrict__ Wv,
                                                bf16_t* __restrict__ QA,
                                                bf16_t* __restrict__ Kp,
                                                bf16_t* __restrict__ VpT,
                                                const int* __restrict__ flag) {
    const int f = *flag;  // 1 => fp32 inputs

    __shared__ bf16_t As[128 * KP];
    __shared__ bf16_t Ws[64 * KP];

    const int tid = threadIdx.x;
    const int wave = tid >> 6, lane = tid & 63;
    const int lo = lane & 15, quad = lane >> 4;
    const int rb = wave * 32;               // wave's row band
    const int cb = blockIdx.x;              // 0..17
    const int rowBase = blockIdx.y * 128;

    floatx4 acc[2][4];
#pragma unroll
    for (int i = 0; i < 2; i++)
#pragma unroll
        for (int j = 0; j < 4; j++) acc[i][j] = (floatx4){0.f, 0.f, 0.f, 0.f};

    if (f) {
        const int rA = tid >> 3, sg = tid & 7;
        const float* arow[4];
        const float* wrow[2];
#pragma unroll
        for (int p = 0; p < 4; p++)
            arow[p] = (const float*)X + (size_t)(rowBase + rA + 32 * p) * DD;
#pragma unroll
        for (int p = 0; p < 2; p++) {
            int row = rA + 32 * p;  // 0..63
            if (cb < 16)       wrow[p] = (const float*)Wq + (size_t)(cb * 64 + row) * DD;
            else if (cb == 16) wrow[p] = (const float*)Wk + (size_t)row * DD;
            else               wrow[p] = (const float*)Wv + (size_t)row * DD;
        }
        float4 aR[4], wR[2];
#pragma unroll
        for (int p = 0; p < 4; p++) aR[p] = *(const float4*)(arow[p] + sg * 4);
#pragma unroll
        for (int p = 0; p < 2; p++) wR[p] = *(const float4*)(wrow[p] + sg * 4);

        for (int k0 = 0; k0 < DD; k0 += BK) {
            __syncthreads();
#pragma unroll
            for (int p = 0; p < 4; p++)
                *(bf16x4*)&As[(rA + 32 * p) * KP + sg * 4] = cvt4(aR[p]);
#pragma unroll
            for (int p = 0; p < 2; p++)
                *(bf16x4*)&Ws[(rA + 32 * p) * KP + sg * 4] = cvt4(wR[p]);
            __syncthreads();
            if (k0 + BK < DD) {
#pragma unroll
                for (int p = 0; p < 4; p++) aR[p] = *(const float4*)(arow[p] + k0 + BK + sg * 4);
#pragma unroll
                for (int p = 0; p < 2; p++) wR[p] = *(const float4*)(wrow[p] + k0 + BK + sg * 4);
            }
            bf16x8 afr[2], bfr[4];
#pragma unroll
            for (int i = 0; i < 2; i++)
                afr[i] = *(const bf16x8*)&As[(rb + i * 16 + lo) * KP + quad * 8];
#pragma unroll
            for (int j = 0; j < 4; j++)
                bfr[j] = *(const bf16x8*)&Ws[(j * 16 + lo) * KP + quad * 8];
#pragma unroll
            for (int i = 0; i < 2; i++)
#pragma unroll
                for (int j = 0; j < 4; j++)
                    acc[i][j] = __builtin_amdgcn_mfma_f32_16x16x32_bf16(afr[i], bfr[j], acc[i][j], 0, 0, 0);
        }
    } else {
        const int rA = tid >> 2, sg = tid & 3;   // rA 0..63
        const bf16_t* arow[2];
        const bf16_t* wrow;
#pragma unroll
        for (int p = 0; p < 2; p++)
            arow[p] = (const bf16_t*)X + (size_t)(rowBase + rA + 64 * p) * DD;
        if (cb < 16)       wrow = (const bf16_t*)Wq + (size_t)(cb * 64 + rA) * DD;
        else if (cb == 16) wrow = (const bf16_t*)Wk + (size_t)rA * DD;
        else               wrow = (const bf16_t*)Wv + (size_t)rA * DD;
        bf16x8 aR[2], wR;
#pragma unroll
        for (int p = 0; p < 2; p++) aR[p] = *(const bf16x8*)(arow[p] + sg * 8);
        wR = *(const bf16x8*)(wrow + sg * 8);

        for (int k0 = 0; k0 < DD; k0 += BK) {
            __syncthreads();
#pragma unroll
            for (int p = 0; p < 2; p++)
                *(bf16x8*)&As[(rA + 64 * p) * KP + sg * 8] = aR[p];
            *(bf16x8*)&Ws[rA * KP + sg * 8] = wR;
            __syncthreads();
            if (k0 + BK < DD) {
#pragma unroll
                for (int p = 0; p < 2; p++) aR[p] = *(const bf16x8*)(arow[p] + k0 + BK + sg * 8);
                wR = *(const bf16x8*)(wrow + k0 + BK + sg * 8);
            }
            bf16x8 afr[2], bfr[4];
#pragma unroll
            for (int i = 0; i < 2; i++)
                afr[i] = *(const bf16x8*)&As[(rb + i * 16 + lo) * KP + quad * 8];
#pragma unroll
            for (int j = 0; j < 4; j++)
                bfr[j] = *(const bf16x8*)&Ws[(j * 16 + lo) * KP + quad * 8];
#pragma unroll
            for (int i = 0; i < 2; i++)
#pragma unroll
                for (int j = 0; j < 4; j++)
                    acc[i][j] = __builtin_amdgcn_mfma_f32_16x16x32_bf16(afr[i], bfr[j], acc[i][j], 0, 0, 0);
        }
    }

#pragma unroll
    for (int i = 0; i < 2; i++)
#pragma unroll
        for (int j = 0; j < 4; j++)
#pragma unroll
            for (int reg = 0; reg < 4; reg++) {
                int row = rowBase + rb + i * 16 + quad * 4 + reg;  // token
                int col = j * 16 + lo;                              // 0..63
                bf16_t val = (bf16_t)acc[i][j][reg];
                if (cb < 16)       QA[(size_t)row * DD + cb * 64 + col] = val;
                else if (cb == 16) Kp[(size_t)row * HD + col] = val;
                else               VpT[((size_t)(row >> 11) * HD + col) * SS + (row & (SS - 1))] = val;
            }
}

__global__ __launch_bounds__(256) void proj_o(const bf16_t* __restrict__ AO,
                                              const void* __restrict__ Wo,
                                              void* __restrict__ Cout,
                                              const int* __restrict__ flag) {
    const int f = *flag;

    __shared__ bf16_t As[128 * KP];
    __shared__ bf16_t Ws[64 * KP];

    const int tid = threadIdx.x;
    const int wave = tid >> 6, lane = tid & 63;
    const int lo = lane & 15, quad = lane >> 4;
    const int rb = wave * 32;
    const int colBase = blockIdx.x * 64;
    const int rowBase = blockIdx.y * 128;

    floatx4 acc[2][4];
#pragma unroll
    for (int i = 0; i < 2; i++)
#pragma unroll
        for (int j = 0; j < 4; j++) acc[i][j] = (floatx4){0.f, 0.f, 0.f, 0.f};

    // A staging (bf16 always)
    const int rA2 = tid >> 2, sgA = tid & 3;
    const bf16_t* arow[2] = {AO + (size_t)(rowBase + rA2) * DD,
                             AO + (size_t)(rowBase + rA2 + 64) * DD};
    bf16x8 aR[2];
#pragma unroll
    for (int p = 0; p < 2; p++) aR[p] = *(const bf16x8*)(arow[p] + sgA * 8);

    if (f) {
        const int rW = tid >> 3, sgW = tid & 7;
        const float* wrow[2];
#pragma unroll
        for (int p = 0; p < 2; p++)
            wrow[p] = (const float*)Wo + (size_t)(colBase + rW + 32 * p) * DD;
        float4 wR[2];
#pragma unroll
        for (int p = 0; p < 2; p++) wR[p] = *(const float4*)(wrow[p] + sgW * 4);

        for (int k0 = 0; k0 < DD; k0 += BK) {
            __syncthreads();
#pragma unroll
            for (int p = 0; p < 2; p++)
                *(bf16x8*)&As[(rA2 + 64 * p) * KP + sgA * 8] = aR[p];
#pragma unroll
            for (int p = 0; p < 2; p++)
                *(bf16x4*)&Ws[(rW + 32 * p) * KP + sgW * 4] = cvt4(wR[p]);
            __syncthreads();
            if (k0 + BK < DD) {
#pragma unroll
                for (int p = 0; p < 2; p++) aR[p] = *(const bf16x8*)(arow[p] + k0 + BK + sgA * 8);
#pragma unroll
                for (int p = 0; p < 2; p++) wR[p] = *(const float4*)(wrow[p] + k0 + BK + sgW * 4);
            }
            bf16x8 afr[2], bfr[4];
#pragma unroll
            for (int i = 0; i < 2; i++)
                afr[i] = *(const bf16x8*)&As[(rb + i * 16 + lo) * KP + quad * 8];
#pragma unroll
            for (int j = 0; j < 4; j++)
                bfr[j] = *(const bf16x8*)&Ws[(j * 16 + lo) * KP + quad * 8];
#pragma unroll
            for (int i = 0; i < 2; i++)
#pragma unroll
                for (int j = 0; j < 4; j++)
                    acc[i][j] = __builtin_amdgcn_mfma_f32_16x16x32_bf16(afr[i], bfr[j], acc[i][j], 0, 0, 0);
        }
    } else {
        const bf16_t* wrow = (const bf16_t*)Wo + (size_t)(colBase + rA2) * DD;
        bf16x8 wR = *(const bf16x8*)(wrow + sgA * 8);

        for (int k0 = 0; k0 < DD; k0 += BK) {
            __syncthreads();
#pragma unroll
            for (int p = 0; p < 2; p++)
                *(bf16x8*)&As[(rA2 + 64 * p) * KP + sgA * 8] = aR[p];
            *(bf16x8*)&Ws[rA2 * KP + sgA * 8] = wR;
            __syncthreads();
            if (k0 + BK < DD) {
#pragma unroll
                for (int p = 0; p < 2; p++) aR[p] = *(const bf16x8*)(arow[p] + k0 + BK + sgA * 8);
                wR = *(const bf16x8*)(wrow + k0 + BK + sgA * 8);
            }
            bf16x8 afr[2], bfr[4];
#pragma unroll
            for (int i = 0; i < 2; i++)
                afr[i] = *(const bf16x8*)&As[(rb + i * 16 + lo) * KP + quad * 8];
#pragma unroll
            for (int j = 0; j < 4; j++)
                bfr[j] = *(const bf16x8*)&Ws[(j * 16 + lo) * KP + quad * 8];
#pragma unroll
            for (int i = 0; i < 2; i++)
#pragma unroll
                for (int j = 0; j < 4; j++)
                    acc[i][j] = __builtin_amdgcn_mfma_f32_16x16x32_bf16(afr[i], bfr[j], acc[i][j], 0, 0, 0);
        }
    }

#pragma unroll
    for (int i = 0; i < 2; i++)
#pragma unroll
        for (int j = 0; j < 4; j++)
#pragma unroll
            for (int reg = 0; reg < 4; reg++) {
                int row = rowBase + rb + i * 16 + quad * 4 + reg;
                int col = colBase + j * 16 + lo;
                size_t idx = (size_t)row * DD + col;
                if (f) ((float*)Cout)[idx] = acc[i][j][reg];
                else   ((bf16_t*)Cout)[idx] = (bf16_t)acc[i][j][reg];
            }
}

// ---------------- barrier-free MFMA flash attention, balanced key-split ----
// 512-thread blocks (8 waves), pair (x, 63-x): exactly 65 key-tiles of work
// per block regardless of x -> block balance by construction. Waves are
// assigned proportionally (worst wave ~10 tiles vs 32 in the unbalanced
// version); partials merge with a binary tree through LDS.
// __launch_bounds__(512, 4): 128-VGPR budget — the (512,8)/64-VGPR variant
// spilled catastrophically (1.5 GB scratch traffic, 4x slower). 16 waves/CU.
#define PSTR 40
#define ALOG2E 0.18033688011112042f   // (1/sqrt(64)) * log2(e)

__global__ __launch_bounds__(512, 4) void attn_mfma(const bf16_t* Q,
                                                    const bf16_t* __restrict__ K,
                                                    const bf16_t* __restrict__ Vt,
                                                    bf16_t* O) {
    const int h = blockIdx.y, b = blockIdx.z;
    const int tid = threadIdx.x;
    const int wq = tid >> 6, lane = tid & 63;
    const int lo = lane & 15, quad = lane >> 4;
    const int x = blockIdx.x;           // 0..31 -> pair (x, 63-x)

    // --- proportional wave->q-tile assignment (minimize max wave tiles) ---
    const int nA = x + 1;               // key-tiles for qt = x (pair total 65)
    int na = 1, bestc = 0x7fffffff;
#pragma unroll
    for (int a = 1; a <= 7; ++a) {
        int cA = (nA + a - 1) / a;
        int cB = (65 - nA + (7 - a)) / (8 - a);
        int c = cA > cB ? cA : cB;
        if (c < bestc) { bestc = c; na = a; }
    }
    int qt, pos, gs;
    if (wq < na) { qt = x;      pos = wq;      gs = na; }
    else         { qt = 63 - x; pos = wq - na; gs = 8 - na; }
    const int q0 = qt * 32;
    const int n = qt + 1;               // total key-tiles for this q-tile
    const int itS = (n * pos) / gs;
    const int itE = (n * (pos + 1)) / gs;

    // --- LDS: P staging (per-wave, loop phase) unions merge buffers ---
    __shared__ __align__(16) char smem[4 * 32 * 64 * 4];  // 32768 B
    __shared__ float MrgML[4][2][2][16];                  // [buf][s][m/l][lo]
    bf16_t* Pw = (bf16_t*)smem + wq * (32 * PSTR);        // 8 x 2560 B = 20480 B
    float (*MrgO)[32 * 64] = (float (*)[32 * 64])smem;    // 4 bufs x 8 KB

    // Q frags (B operand: n=q, k=dim)
    bf16x8 qf[2][2];
#pragma unroll
    for (int s = 0; s < 2; s++)
#pragma unroll
        for (int hf = 0; hf < 2; hf++)
            qf[s][hf] = *(const bf16x8*)(Q + ((size_t)(b * SS + q0 + s * 16 + lo)) * DD +
                                         h * HD + hf * 32 + quad * 8);

    floatx4 Oacc[2][4];
    float m_i[2], l_i[2];
#pragma unroll
    for (int s = 0; s < 2; s++) {
#pragma unroll
        for (int dt = 0; dt < 4; dt++) Oacc[s][dt] = (floatx4){0.f, 0.f, 0.f, 0.f};
        m_i[s] = -1e30f; l_i[s] = 0.f;
    }

    const bf16_t* Kb = K + (size_t)b * SS * HD;
    const bf16_t* Vb = Vt + (size_t)b * HD * SS;

    if (itS < itE) {
        // preload K tile itS
        bf16x8 kf[2][2];
#pragma unroll
        for (int kt = 0; kt < 2; kt++)
#pragma unroll
            for (int hf = 0; hf < 2; hf++)
                kf[kt][hf] = *(const bf16x8*)(Kb + (size_t)(itS * 32 + kt * 16 + lo) * HD +
                                              hf * 32 + quad * 8);

        for (int it = itS; it < itE; it++) {
            const int t0 = it * 32;

            bf16x8 vf[4];
#pragma unroll
            for (int dt = 0; dt < 4; dt++)
                vf[dt] = *(const bf16x8*)(Vb + (size_t)(dt * 16 + lo) * SS + t0 + quad * 8);

            bf16x8 kn[2][2];
            if (it + 1 < itE) {
#pragma unroll
                for (int kt = 0; kt < 2; kt++)
#pragma unroll
                    for (int hf = 0; hf < 2; hf++)
                        kn[kt][hf] = *(const bf16x8*)(Kb + (size_t)(t0 + 32 + kt * 16 + lo) * HD +
                                                      hf * 32 + quad * 8);
            }

            // S^T = K.Q^T
            floatx4 st[2][2];
#pragma unroll
            for (int s = 0; s < 2; s++)
#pragma unroll
                for (int kt = 0; kt < 2; kt++) {
                    floatx4 z = (floatx4){0.f, 0.f, 0.f, 0.f};
                    z = __builtin_amdgcn_mfma_f32_16x16x32_bf16(kf[kt][0], qf[s][0], z, 0, 0, 0);
                    z = __builtin_amdgcn_mfma_f32_16x16x32_bf16(kf[kt][1], qf[s][1], z, 0, 0, 0);
                    st[s][kt] = z;
                }

            if (it == qt) {  // diagonal tile (always last pos of the group)
#pragma unroll
                for (int s = 0; s < 2; s++) {
                    int q = q0 + s * 16 + lo;
#pragma unroll
                    for (int kt = 0; kt < 2; kt++)
#pragma unroll
                        for (int reg = 0; reg < 4; reg++)
                            if (t0 + kt * 16 + quad * 4 + reg > q) st[s][kt][reg] = -1e30f;
                }
            }

            // online softmax, lane-owned q-rows
#pragma unroll
            for (int s = 0; s < 2; s++) {
                float mx = fmaxf(fmaxf(fmaxf(st[s][0][0], st[s][0][1]), fmaxf(st[s][0][2], st[s][0][3])),
                                 fmaxf(fmaxf(st[s][1][0], st[s][1][1]), fmaxf(st[s][1][2], st[s][1][3])));
                mx = fmaxf(mx, __shfl_xor(mx, 16));
                mx = fmaxf(mx, __shfl_xor(mx, 32));
                float mn = fmaxf(m_i[s], mx);
                float al = exp2f((m_i[s] - mn) * ALOG2E);
                m_i[s] = mn;
                float mnA = mn * ALOG2E;
                float p[2][4];
#pragma unroll
                for (int kt = 0; kt < 2; kt++)
#pragma unroll
                    for (int reg = 0; reg < 4; reg++)
                        p[kt][reg] = exp2f(st[s][kt][reg] * ALOG2E - mnA);
                float rs = ((p[0][0] + p[0][1]) + (p[0][2] + p[0][3])) +
                           ((p[1][0] + p[1][1]) + (p[1][2] + p[1][3]));
                rs += __shfl_xor(rs, 16);
                rs += __shfl_xor(rs, 32);
                l_i[s] = l_i[s] * al + rs;
#pragma unroll
                for (int kt = 0; kt < 2; kt++) {
                    bf16x4 pk;
#pragma unroll
                    for (int reg = 0; reg < 4; reg++) pk[reg] = (bf16_t)p[kt][reg];
                    *(bf16x4*)&Pw[(s * 16 + lo) * PSTR + kt * 16 + quad * 4] = pk;
                }
#pragma unroll
                for (int dt = 0; dt < 4; dt++) Oacc[s][dt] *= al;
            }

            asm volatile("s_waitcnt lgkmcnt(0)" ::: "memory");

            // O^T += V^T . P^T
            bf16x8 pb[2];
#pragma unroll
            for (int s = 0; s < 2; s++)
                pb[s] = *(const bf16x8*)&Pw[(s * 16 + lo) * PSTR + quad * 8];
#pragma unroll
            for (int s = 0; s < 2; s++)
#pragma unroll
                for (int dt = 0; dt < 4; dt++)
                    Oacc[s][dt] = __builtin_amdgcn_mfma_f32_16x16x32_bf16(vf[dt], pb[s], Oacc[s][dt], 0, 0, 0);

#pragma unroll
            for (int kt = 0; kt < 2; kt++)
#pragma unroll
                for (int hf = 0; hf < 2; hf++) kf[kt][hf] = kn[kt][hf];
        }
    }

    // ---- binary-tree merge within each wave group (flash merge algebra) ----
    // Publishers (pos % 2*step == step) write (m,l,O^T) to buffer wq>>1;
    // combiners (pos % 2*step == 0, partner in range) fold partner's buffer
    // ((wq+step)>>1) into registers. Division deferred to the final store.
    for (int step = 1; step < 8; step <<= 1) {
        const bool pub = (pos & (2 * step - 1)) == step;
        const bool cmb = ((pos & (2 * step - 1)) == 0) && (pos + step < gs);
        __syncthreads();   // previous round's reads (and P-staging use) done
        if (pub) {
            float* Ob = MrgO[wq >> 1];
#pragma unroll
            for (int s = 0; s < 2; s++) {
#pragma unroll
                for (int dt = 0; dt < 4; dt++)
#pragma unroll
                    for (int reg = 0; reg < 4; reg++)
                        Ob[(s * 16 + dt * 4 + reg) * 64 + lane] = Oacc[s][dt][reg];
                if (quad == 0) {
                    MrgML[wq >> 1][s][0][lo] = m_i[s];
                    MrgML[wq >> 1][s][1][lo] = l_i[s];
                }
            }
        }
        __syncthreads();
        if (cmb) {
            const int bu = (wq + step) >> 1;
            const float* Ob = MrgO[bu];
#pragma unroll
            for (int s = 0; s < 2; s++) {
                float m1 = MrgML[bu][s][0][lo];
                float l1 = MrgML[bu][s][1][lo];
                float mm = fmaxf(m_i[s], m1);
                float a0 = exp2f((m_i[s] - mm) * ALOG2E);
                float a1 = exp2f((m1 - mm) * ALOG2E);
                m_i[s] = mm;
                l_i[s] = l_i[s] * a0 + l1 * a1;
#pragma unroll
                for (int dt = 0; dt < 4; dt++)
#pragma unroll
                    for (int reg = 0; reg < 4; reg++)
                        Oacc[s][dt][reg] = Oacc[s][dt][reg] * a0 +
                                           Ob[(s * 16 + dt * 4 + reg) * 64 + lane] * a1;
            }
        }
    }

    // ---- group leaders (pos==0: waves 0 and na) finalize + store ----
    if (pos == 0) {
#pragma unroll
        for (int s = 0; s < 2; s++) {
            float linv = 1.f / l_i[s];
            bf16_t* Orow = O + ((size_t)(b * SS + q0 + s * 16 + lo)) * DD + h * HD;
#pragma unroll
            for (int dt = 0; dt < 4; dt++) {
                bf16x4 ov;
#pragma unroll
                for (int reg = 0; reg < 4; reg++)
                    ov[reg] = (bf16_t)(Oacc[s][dt][reg] * linv);
                *(bf16x4*)&Orow[dt * 16 + quad * 4] = ov;
            }
        }
    }
}

// ---------------- launch ----------------
extern "C" void kernel_launch(void* const* d_in, const int* in_sizes, int n_in,
                              void* d_out, int out_size, void* d_ws, size_t ws_size,
                              hipStream_t stream) {
    const void* x  = d_in[0];
    const void* Wq = d_in[1];
    const void* Wk = d_in[2];
    const void* Wv = d_in[3];
    const void* Wo = d_in[4];
    // d_in[5] = causal mask — known tril, handled analytically in attn_mfma.

    // Workspace (~9.0 MB): [flag 256B] | QA bf16[4096,1024] (Q -> attention
    // output in-place) | Kp bf16[4096,64] | VpT bf16[2][64][2048]
    char* ws = (char*)d_ws;
    int* flag = (int*)ws;
    bf16_t* QA  = (bf16_t*)(ws + 256);
    bf16_t* Kp  = QA + (size_t)MM * DD;
    bf16_t* VpT = Kp + (size_t)MM * HD;

    detect_dtype<<<1, 64, 0, stream>>>((const unsigned int*)x, flag);

    // 128x64 tiles: 18x32 = 576 blocks (~2.25/CU)
    proj_qkv<<<dim3(18, MM / 128), dim3(256), 0, stream>>>(x, Wq, Wk, Wv, QA, Kp, VpT, flag);

    // Balanced pair-blocks: 32 x NH x BB = 1024 blocks of 512 thr
    attn_mfma<<<dim3(32, NH, BB), dim3(512), 0, stream>>>(QA, Kp, VpT, QA);

    // 128x64 tiles: 16x32 = 512 blocks (2/CU)
    proj_o<<<dim3(16, MM / 128), dim3(256), 0, stream>>>(QA, Wo, d_out, flag);
}

// Round 3
// 219.044 us; speedup vs baseline: 2.1631x; 1.0079x over previous
//
#include <hip/hip_runtime.h>
#include <hip/hip_bf16.h>
#include <math.h>

// Problem constants (MultiQueryAttention: B=2, S=2048, D=1024, H=16, hd=64)
#define BB 2
#define SS 2048
#define DD 1024
#define NH 16
#define HD 64
#define MM (BB * SS)  // 4096 tokens

typedef __hip_bfloat16 bf16;
typedef __bf16 bf16_t;
typedef __attribute__((ext_vector_type(8))) __bf16 bf16x8;
typedef __attribute__((ext_vector_type(4))) __bf16 bf16x4;
typedef __attribute__((ext_vector_type(4))) float floatx4;

// (1/sqrt(64)) * log2(e): folded into Q at projection time so QK^T scores
// come out directly in the exp2 domain (saves 16 muls/iter in attention).
#define SCALEQ 0.18033688011112042f

// ---------------- runtime dtype detection (parallel) ----------------
// flag==1 -> external tensors are fp32 (the proven world); flag==0 -> bf16.
__global__ void detect_dtype(const unsigned int* __restrict__ x, int* __restrict__ flag) {
    const int tid = threadIdx.x;  // 64 lanes
    int good = 0;
    for (int i = tid; i < 256; i += 64) {
        unsigned int bits = (x[i] & 0xFFFFu) << 16;
        float v = __uint_as_float(bits);
        float av = fabsf(v);
        if (av == 0.f || (av >= 9.5367431640625e-7f && av <= 64.f)) good++;
    }
#pragma unroll
    for (int s = 1; s < 64; s <<= 1) good += __shfl_xor(good, s);
    if (tid == 0) *flag = (good >= 240) ? 0 : 1;
}

// ---------------- MFMA projection GEMMs ----------------
// 128(rows)x64(cols) tiles, BK=32, 4 waves (each: 32 rows x 64 cols, 8 MFMA
// per iter).
#define BK 32
#define KP 40   // LDS row stride in bf16 elems

__device__ __forceinline__ bf16x4 cvt4(float4 v) {
    bf16x4 o;
    o[0] = (bf16_t)v.x; o[1] = (bf16_t)v.y; o[2] = (bf16_t)v.z; o[3] = (bf16_t)v.w;
    return o;
}

// Fused QKV projection. cb 0..15 -> QA cols cb*64.. (pre-scaled by SCALEQ);
// cb 16 -> Kp; cb 17 -> VpT.
__global__ __launch_bounds__(256) void proj_qkv(const void* __restrict__ X,
                                                const void* __restrict__ Wq,
                                                const void* __restrict__ Wk,
                                                const void* __restrict__ Wv,
                                                bf16_t* __restrict__ QA,
                                                bf16_t* __restrict__ Kp,
                                                bf16_t* __restrict__ VpT,
                                                const int* __restrict__ flag) {
    const int f = *flag;  // 1 => fp32 inputs

    __shared__ bf16_t As[128 * KP];
    __shared__ bf16_t Ws[64 * KP];

    const int tid = threadIdx.x;
    const int wave = tid >> 6, lane = tid & 63;
    const int lo = lane & 15, quad = lane >> 4;
    const int rb = wave * 32;               // wave's row band
    const int cb = blockIdx.x;              // 0..17
    const int rowBase = blockIdx.y * 128;

    floatx4 acc[2][4];
#pragma unroll
    for (int i = 0; i < 2; i++)
#pragma unroll
        for (int j = 0; j < 4; j++) acc[i][j] = (floatx4){0.f, 0.f, 0.f, 0.f};

    if (f) {
        const int rA = tid >> 3, sg = tid & 7;
        const float* arow[4];
        const float* wrow[2];
#pragma unroll
        for (int p = 0; p < 4; p++)
            arow[p] = (const float*)X + (size_t)(rowBase + rA + 32 * p) * DD;
#pragma unroll
        for (int p = 0; p < 2; p++) {
            int row = rA + 32 * p;  // 0..63
            if (cb < 16)       wrow[p] = (const float*)Wq + (size_t)(cb * 64 + row) * DD;
            else if (cb == 16) wrow[p] = (const float*)Wk + (size_t)row * DD;
            else               wrow[p] = (const float*)Wv + (size_t)row * DD;
        }
        float4 aR[4], wR[2];
#pragma unroll
        for (int p = 0; p < 4; p++) aR[p] = *(const float4*)(arow[p] + sg * 4);
#pragma unroll
        for (int p = 0; p < 2; p++) wR[p] = *(const float4*)(wrow[p] + sg * 4);

        for (int k0 = 0; k0 < DD; k0 += BK) {
            __syncthreads();
#pragma unroll
            for (int p = 0; p < 4; p++)
                *(bf16x4*)&As[(rA + 32 * p) * KP + sg * 4] = cvt4(aR[p]);
#pragma unroll
            for (int p = 0; p < 2; p++)
                *(bf16x4*)&Ws[(rA + 32 * p) * KP + sg * 4] = cvt4(wR[p]);
            __syncthreads();
            if (k0 + BK < DD) {
#pragma unroll
                for (int p = 0; p < 4; p++) aR[p] = *(const float4*)(arow[p] + k0 + BK + sg * 4);
#pragma unroll
                for (int p = 0; p < 2; p++) wR[p] = *(const float4*)(wrow[p] + k0 + BK + sg * 4);
            }
            bf16x8 afr[2], bfr[4];
#pragma unroll
            for (int i = 0; i < 2; i++)
                afr[i] = *(const bf16x8*)&As[(rb + i * 16 + lo) * KP + quad * 8];
#pragma unroll
            for (int j = 0; j < 4; j++)
                bfr[j] = *(const bf16x8*)&Ws[(j * 16 + lo) * KP + quad * 8];
#pragma unroll
            for (int i = 0; i < 2; i++)
#pragma unroll
                for (int j = 0; j < 4; j++)
                    acc[i][j] = __builtin_amdgcn_mfma_f32_16x16x32_bf16(afr[i], bfr[j], acc[i][j], 0, 0, 0);
        }
    } else {
        const int rA = tid >> 2, sg = tid & 3;   // rA 0..63
        const bf16_t* arow[2];
        const bf16_t* wrow;
#pragma unroll
        for (int p = 0; p < 2; p++)
            arow[p] = (const bf16_t*)X + (size_t)(rowBase + rA + 64 * p) * DD;
        if (cb < 16)       wrow = (const bf16_t*)Wq + (size_t)(cb * 64 + rA) * DD;
        else if (cb == 16) wrow = (const bf16_t*)Wk + (size_t)rA * DD;
        else               wrow = (const bf16_t*)Wv + (size_t)rA * DD;
        bf16x8 aR[2], wR;
#pragma unroll
        for (int p = 0; p < 2; p++) aR[p] = *(const bf16x8*)(arow[p] + sg * 8);
        wR = *(const bf16x8*)(wrow + sg * 8);

        for (int k0 = 0; k0 < DD; k0 += BK) {
            __syncthreads();
#pragma unroll
            for (int p = 0; p < 2; p++)
                *(bf16x8*)&As[(rA + 64 * p) * KP + sg * 8] = aR[p];
            *(bf16x8*)&Ws[rA * KP + sg * 8] = wR;
            __syncthreads();
            if (k0 + BK < DD) {
#pragma unroll
                for (int p = 0; p < 2; p++) aR[p] = *(const bf16x8*)(arow[p] + k0 + BK + sg * 8);
                wR = *(const bf16x8*)(wrow + k0 + BK + sg * 8);
            }
            bf16x8 afr[2], bfr[4];
#pragma unroll
            for (int i = 0; i < 2; i++)
                afr[i] = *(const bf16x8*)&As[(rb + i * 16 + lo) * KP + quad * 8];
#pragma unroll
            for (int j = 0; j < 4; j++)
                bfr[j] = *(const bf16x8*)&Ws[(j * 16 + lo) * KP + quad * 8];
#pragma unroll
            for (int i = 0; i < 2; i++)
#pragma unroll
                for (int j = 0; j < 4; j++)
                    acc[i][j] = __builtin_amdgcn_mfma_f32_16x16x32_bf16(afr[i], bfr[j], acc[i][j], 0, 0, 0);
        }
    }

#pragma unroll
    for (int i = 0; i < 2; i++)
#pragma unroll
        for (int j = 0; j < 4; j++)
#pragma unroll
            for (int reg = 0; reg < 4; reg++) {
                int row = rowBase + rb + i * 16 + quad * 4 + reg;  // token
                int col = j * 16 + lo;                              // 0..63
                if (cb < 16) {
                    // Q: pre-scale so QK^T is already in the exp2 domain
                    QA[(size_t)row * DD + cb * 64 + col] = (bf16_t)(acc[i][j][reg] * SCALEQ);
                } else if (cb == 16) {
                    Kp[(size_t)row * HD + col] = (bf16_t)acc[i][j][reg];
                } else {
                    VpT[((size_t)(row >> 11) * HD + col) * SS + (row & (SS - 1))] =
                        (bf16_t)acc[i][j][reg];
                }
            }
}

__global__ __launch_bounds__(256) void proj_o(const bf16_t* __restrict__ AO,
                                              const void* __restrict__ Wo,
                                              void* __restrict__ Cout,
                                              const int* __restrict__ flag) {
    const int f = *flag;

    __shared__ bf16_t As[128 * KP];
    __shared__ bf16_t Ws[64 * KP];

    const int tid = threadIdx.x;
    const int wave = tid >> 6, lane = tid & 63;
    const int lo = lane & 15, quad = lane >> 4;
    const int rb = wave * 32;
    const int colBase = blockIdx.x * 64;
    const int rowBase = blockIdx.y * 128;

    floatx4 acc[2][4];
#pragma unroll
    for (int i = 0; i < 2; i++)
#pragma unroll
        for (int j = 0; j < 4; j++) acc[i][j] = (floatx4){0.f, 0.f, 0.f, 0.f};

    // A staging (bf16 always)
    const int rA2 = tid >> 2, sgA = tid & 3;
    const bf16_t* arow[2] = {AO + (size_t)(rowBase + rA2) * DD,
                             AO + (size_t)(rowBase + rA2 + 64) * DD};
    bf16x8 aR[2];
#pragma unroll
    for (int p = 0; p < 2; p++) aR[p] = *(const bf16x8*)(arow[p] + sgA * 8);

    if (f) {
        const int rW = tid >> 3, sgW = tid & 7;
        const float* wrow[2];
#pragma unroll
        for (int p = 0; p < 2; p++)
            wrow[p] = (const float*)Wo + (size_t)(colBase + rW + 32 * p) * DD;
        float4 wR[2];
#pragma unroll
        for (int p = 0; p < 2; p++) wR[p] = *(const float4*)(wrow[p] + sgW * 4);

        for (int k0 = 0; k0 < DD; k0 += BK) {
            __syncthreads();
#pragma unroll
            for (int p = 0; p < 2; p++)
                *(bf16x8*)&As[(rA2 + 64 * p) * KP + sgA * 8] = aR[p];
#pragma unroll
            for (int p = 0; p < 2; p++)
                *(bf16x4*)&Ws[(rW + 32 * p) * KP + sgW * 4] = cvt4(wR[p]);
            __syncthreads();
            if (k0 + BK < DD) {
#pragma unroll
                for (int p = 0; p < 2; p++) aR[p] = *(const bf16x8*)(arow[p] + k0 + BK + sgA * 8);
#pragma unroll
                for (int p = 0; p < 2; p++) wR[p] = *(const float4*)(wrow[p] + k0 + BK + sgW * 4);
            }
            bf16x8 afr[2], bfr[4];
#pragma unroll
            for (int i = 0; i < 2; i++)
                afr[i] = *(const bf16x8*)&As[(rb + i * 16 + lo) * KP + quad * 8];
#pragma unroll
            for (int j = 0; j < 4; j++)
                bfr[j] = *(const bf16x8*)&Ws[(j * 16 + lo) * KP + quad * 8];
#pragma unroll
            for (int i = 0; i < 2; i++)
#pragma unroll
                for (int j = 0; j < 4; j++)
                    acc[i][j] = __builtin_amdgcn_mfma_f32_16x16x32_bf16(afr[i], bfr[j], acc[i][j], 0, 0, 0);
        }
    } else {
        const bf16_t* wrow = (const bf16_t*)Wo + (size_t)(colBase + rA2) * DD;
        bf16x8 wR = *(const bf16x8*)(wrow + sgA * 8);

        for (int k0 = 0; k0 < DD; k0 += BK) {
            __syncthreads();
#pragma unroll
            for (int p = 0; p < 2; p++)
                *(bf16x8*)&As[(rA2 + 64 * p) * KP + sgA * 8] = aR[p];
            *(bf16x8*)&Ws[rA2 * KP + sgA * 8] = wR;
            __syncthreads();
            if (k0 + BK < DD) {
#pragma unroll
                for (int p = 0; p < 2; p++) aR[p] = *(const bf16x8*)(arow[p] + k0 + BK + sgA * 8);
                wR = *(const bf16x8*)(wrow + k0 + BK + sgA * 8);
            }
            bf16x8 afr[2], bfr[4];
#pragma unroll
            for (int i = 0; i < 2; i++)
                afr[i] = *(const bf16x8*)&As[(rb + i * 16 + lo) * KP + quad * 8];
#pragma unroll
            for (int j = 0; j < 4; j++)
                bfr[j] = *(const bf16x8*)&Ws[(j * 16 + lo) * KP + quad * 8];
#pragma unroll
            for (int i = 0; i < 2; i++)
#pragma unroll
                for (int j = 0; j < 4; j++)
                    acc[i][j] = __builtin_amdgcn_mfma_f32_16x16x32_bf16(afr[i], bfr[j], acc[i][j], 0, 0, 0);
        }
    }

#pragma unroll
    for (int i = 0; i < 2; i++)
#pragma unroll
        for (int j = 0; j < 4; j++)
#pragma unroll
            for (int reg = 0; reg < 4; reg++) {
                int row = rowBase + rb + i * 16 + quad * 4 + reg;
                int col = colBase + j * 16 + lo;
                size_t idx = (size_t)row * DD + col;
                if (f) ((float*)Cout)[idx] = acc[i][j][reg];
                else   ((bf16_t*)Cout)[idx] = (bf16_t)acc[i][j][reg];
            }
}

// ---------------- barrier-free MFMA flash attention, balanced key-split ----
// 512-thread blocks (8 waves), pair (x, 63-x): 65 key-tiles per block by
// construction; waves assigned proportionally (worst ~10 tiles). Softmax is
// defer-max (T13): Q is pre-scaled into the exp2 domain, a wave-uniform
// __any(localmax > m + 8) trigger guards the cross-lane max reduce + rescale,
// and the denominator l is kept lane-partial (reduced once after the loop).
// Common-case iteration has ZERO cross-lane shuffles. P <= 2^8, safe in bf16.
// __launch_bounds__(512, 4): 128-VGPR budget — (512,8) spilled 1.5 GB.
#define PSTR 40
#define DMTHR 8.0f    // defer-max threshold (exp2 domain)

__global__ __launch_bounds__(512, 4) void attn_mfma(const bf16_t* Q,
                                                    const bf16_t* __restrict__ K,
                                                    const bf16_t* __restrict__ Vt,
                                                    bf16_t* O) {
    const int h = blockIdx.y, b = blockIdx.z;
    const int tid = threadIdx.x;
    const int wq = tid >> 6, lane = tid & 63;
    const int lo = lane & 15, quad = lane >> 4;
    const int x = blockIdx.x;           // 0..31 -> pair (x, 63-x)

    // --- proportional wave->q-tile assignment (minimize max wave tiles) ---
    const int nA = x + 1;               // key-tiles for qt = x (pair total 65)
    int na = 1, bestc = 0x7fffffff;
#pragma unroll
    for (int a = 1; a <= 7; ++a) {
        int cA = (nA + a - 1) / a;
        int cB = (65 - nA + (7 - a)) / (8 - a);
        int c = cA > cB ? cA : cB;
        if (c < bestc) { bestc = c; na = a; }
    }
    int qt, pos, gs;
    if (wq < na) { qt = x;      pos = wq;      gs = na; }
    else         { qt = 63 - x; pos = wq - na; gs = 8 - na; }
    const int q0 = qt * 32;
    const int n = qt + 1;               // total key-tiles for this q-tile
    const int itS = (n * pos) / gs;
    const int itE = (n * (pos + 1)) / gs;

    // --- LDS: P staging (per-wave, loop phase) unions merge buffers ---
    __shared__ __align__(16) char smem[4 * 32 * 64 * 4];  // 32768 B
    __shared__ float MrgML[4][2][2][16];                  // [buf][s][m/l][lo]
    bf16_t* Pw = (bf16_t*)smem + wq * (32 * PSTR);        // 8 x 2560 B = 20480 B
    float (*MrgO)[32 * 64] = (float (*)[32 * 64])smem;    // 4 bufs x 8 KB

    // Q frags (B operand: n=q, k=dim); Q already scaled by (1/8)*log2(e)
    bf16x8 qf[2][2];
#pragma unroll
    for (int s = 0; s < 2; s++)
#pragma unroll
        for (int hf = 0; hf < 2; hf++)
            qf[s][hf] = *(const bf16x8*)(Q + ((size_t)(b * SS + q0 + s * 16 + lo)) * DD +
                                         h * HD + hf * 32 + quad * 8);

    floatx4 Oacc[2][4];
    float m_i[2], l_ln[2];   // m: column-consistent running max; l: LANE-partial
#pragma unroll
    for (int s = 0; s < 2; s++) {
#pragma unroll
        for (int dt = 0; dt < 4; dt++) Oacc[s][dt] = (floatx4){0.f, 0.f, 0.f, 0.f};
        m_i[s] = -1e30f; l_ln[s] = 0.f;
    }

    const bf16_t* Kb = K + (size_t)b * SS * HD;
    const bf16_t* Vb = Vt + (size_t)b * HD * SS;

    if (itS < itE) {
        // preload K tile itS
        bf16x8 kf[2][2];
#pragma unroll
        for (int kt = 0; kt < 2; kt++)
#pragma unroll
            for (int hf = 0; hf < 2; hf++)
                kf[kt][hf] = *(const bf16x8*)(Kb + (size_t)(itS * 32 + kt * 16 + lo) * HD +
                                              hf * 32 + quad * 8);

        for (int it = itS; it < itE; it++) {
            const int t0 = it * 32;

            bf16x8 vf[4];
#pragma unroll
            for (int dt = 0; dt < 4; dt++)
                vf[dt] = *(const bf16x8*)(Vb + (size_t)(dt * 16 + lo) * SS + t0 + quad * 8);

            bf16x8 kn[2][2];
            if (it + 1 < itE) {
#pragma unroll
                for (int kt = 0; kt < 2; kt++)
#pragma unroll
                    for (int hf = 0; hf < 2; hf++)
                        kn[kt][hf] = *(const bf16x8*)(Kb + (size_t)(t0 + 32 + kt * 16 + lo) * HD +
                                                      hf * 32 + quad * 8);
            }

            // S^T = K.Q^T  (already in exp2 domain via pre-scaled Q)
            floatx4 st[2][2];
#pragma unroll
            for (int s = 0; s < 2; s++)
#pragma unroll
                for (int kt = 0; kt < 2; kt++) {
                    floatx4 z = (floatx4){0.f, 0.f, 0.f, 0.f};
                    z = __builtin_amdgcn_mfma_f32_16x16x32_bf16(kf[kt][0], qf[s][0], z, 0, 0, 0);
                    z = __builtin_amdgcn_mfma_f32_16x16x32_bf16(kf[kt][1], qf[s][1], z, 0, 0, 0);
                    st[s][kt] = z;
                }

            if (it == qt) {  // diagonal tile (always last pos of the group)
#pragma unroll
                for (int s = 0; s < 2; s++) {
                    int q = q0 + s * 16 + lo;
#pragma unroll
                    for (int kt = 0; kt < 2; kt++)
#pragma unroll
                        for (int reg = 0; reg < 4; reg++)
                            if (t0 + kt * 16 + quad * 4 + reg > q) st[s][kt][reg] = -1e30f;
                }
            }

            // defer-max online softmax: shuffle-free in the common case
#pragma unroll
            for (int s = 0; s < 2; s++) {
                float lm = fmaxf(fmaxf(fmaxf(st[s][0][0], st[s][0][1]), fmaxf(st[s][0][2], st[s][0][3])),
                                 fmaxf(fmaxf(st[s][1][0], st[s][1][1]), fmaxf(st[s][1][2], st[s][1][3])));
                if (__any(lm > m_i[s] + DMTHR)) {
                    float mx = fmaxf(lm, __shfl_xor(lm, 16));
                    mx = fmaxf(mx, __shfl_xor(mx, 32));
                    float mn = fmaxf(m_i[s], mx);
                    float al = exp2f(m_i[s] - mn);
                    m_i[s] = mn;
                    l_ln[s] *= al;
#pragma unroll
                    for (int dt = 0; dt < 4; dt++) Oacc[s][dt] *= al;
                }
                float p[2][4];
#pragma unroll
                for (int kt = 0; kt < 2; kt++)
#pragma unroll
                    for (int reg = 0; reg < 4; reg++)
                        p[kt][reg] = exp2f(st[s][kt][reg] - m_i[s]);
                l_ln[s] += ((p[0][0] + p[0][1]) + (p[0][2] + p[0][3])) +
                           ((p[1][0] + p[1][1]) + (p[1][2] + p[1][3]));
#pragma unroll
                for (int kt = 0; kt < 2; kt++) {
                    bf16x4 pk;
#pragma unroll
                    for (int reg = 0; reg < 4; reg++) pk[reg] = (bf16_t)p[kt][reg];
                    *(bf16x4*)&Pw[(s * 16 + lo) * PSTR + kt * 16 + quad * 4] = pk;
                }
            }

            asm volatile("s_waitcnt lgkmcnt(0)" ::: "memory");

            // O^T += V^T . P^T
            bf16x8 pb[2];
#pragma unroll
            for (int s = 0; s < 2; s++)
                pb[s] = *(const bf16x8*)&Pw[(s * 16 + lo) * PSTR + quad * 8];
#pragma unroll
            for (int s = 0; s < 2; s++)
#pragma unroll
                for (int dt = 0; dt < 4; dt++)
                    Oacc[s][dt] = __builtin_amdgcn_mfma_f32_16x16x32_bf16(vf[dt], pb[s], Oacc[s][dt], 0, 0, 0);

#pragma unroll
            for (int kt = 0; kt < 2; kt++)
#pragma unroll
                for (int hf = 0; hf < 2; hf++) kf[kt][hf] = kn[kt][hf];
        }
    }

    // ---- finalize lane-partial l into column-consistent l_i ----
    float l_i[2];
#pragma unroll
    for (int s = 0; s < 2; s++) {
        float l = l_ln[s];
        l += __shfl_xor(l, 16);
        l += __shfl_xor(l, 32);
        l_i[s] = l;
    }

    // ---- binary-tree merge within each wave group (flash merge algebra) ----
    for (int step = 1; step < 8; step <<= 1) {
        const bool pub = (pos & (2 * step - 1)) == step;
        const bool cmb = ((pos & (2 * step - 1)) == 0) && (pos + step < gs);
        __syncthreads();   // previous round's reads (and P-staging use) done
        if (pub) {
            float* Ob = MrgO[wq >> 1];
#pragma unroll
            for (int s = 0; s < 2; s++) {
#pragma unroll
                for (int dt = 0; dt < 4; dt++)
#pragma unroll
                    for (int reg = 0; reg < 4; reg++)
                        Ob[(s * 16 + dt * 4 + reg) * 64 + lane] = Oacc[s][dt][reg];
                if (quad == 0) {
                    MrgML[wq >> 1][s][0][lo] = m_i[s];
                    MrgML[wq >> 1][s][1][lo] = l_i[s];
                }
            }
        }
        __syncthreads();
        if (cmb) {
            const int bu = (wq + step) >> 1;
            const float* Ob = MrgO[bu];
#pragma unroll
            for (int s = 0; s < 2; s++) {
                float m1 = MrgML[bu][s][0][lo];
                float l1 = MrgML[bu][s][1][lo];
                float mm = fmaxf(m_i[s], m1);
                float a0 = exp2f(m_i[s] - mm);
                float a1 = exp2f(m1 - mm);
                m_i[s] = mm;
                l_i[s] = l_i[s] * a0 + l1 * a1;
#pragma unroll
                for (int dt = 0; dt < 4; dt++)
#pragma unroll
                    for (int reg = 0; reg < 4; reg++)
                        Oacc[s][dt][reg] = Oacc[s][dt][reg] * a0 +
                                           Ob[(s * 16 + dt * 4 + reg) * 64 + lane] * a1;
            }
        }
    }

    // ---- group leaders (pos==0: waves 0 and na) finalize + store ----
    if (pos == 0) {
#pragma unroll
        for (int s = 0; s < 2; s++) {
            float linv = 1.f / l_i[s];
            bf16_t* Orow = O + ((size_t)(b * SS + q0 + s * 16 + lo)) * DD + h * HD;
#pragma unroll
            for (int dt = 0; dt < 4; dt++) {
                bf16x4 ov;
#pragma unroll
                for (int reg = 0; reg < 4; reg++)
                    ov[reg] = (bf16_t)(Oacc[s][dt][reg] * linv);
                *(bf16x4*)&Orow[dt * 16 + quad * 4] = ov;
            }
        }
    }
}

// ---------------- launch ----------------
extern "C" void kernel_launch(void* const* d_in, const int* in_sizes, int n_in,
                              void* d_out, int out_size, void* d_ws, size_t ws_size,
                              hipStream_t stream) {
    const void* x  = d_in[0];
    const void* Wq = d_in[1];
    const void* Wk = d_in[2];
    const void* Wv = d_in[3];
    const void* Wo = d_in[4];
    // d_in[5] = causal mask — known tril, handled analytically in attn_mfma.

    // Workspace (~9.0 MB): [flag 256B] | QA bf16[4096,1024] (Q -> attention
    // output in-place) | Kp bf16[4096,64] | VpT bf16[2][64][2048]
    char* ws = (char*)d_ws;
    int* flag = (int*)ws;
    bf16_t* QA  = (bf16_t*)(ws + 256);
    bf16_t* Kp  = QA + (size_t)MM * DD;
    bf16_t* VpT = Kp + (size_t)MM * HD;

    detect_dtype<<<1, 64, 0, stream>>>((const unsigned int*)x, flag);

    // 128x64 tiles: 18x32 = 576 blocks (~2.25/CU)
    proj_qkv<<<dim3(18, MM / 128), dim3(256), 0, stream>>>(x, Wq, Wk, Wv, QA, Kp, VpT, flag);

    // Balanced pair-blocks: 32 x NH x BB = 1024 blocks of 512 thr
    attn_mfma<<<dim3(32, NH, BB), dim3(512), 0, stream>>>(QA, Kp, VpT, QA);

    // 128x64 tiles: 16x32 = 512 blocks (2/CU)
    proj_o<<<dim3(16, MM / 128), dim3(256), 0, stream>>>(QA, Wo, d_out, flag);
}